// Round 7
// baseline (19966.705 us; speedup 1.0000x reference)
//
#include <hip/hip_runtime.h>
#include <hip/hip_bf16.h>

// BiLSTM-CRF forward: B=32, T=512, E=512, H=256 (per dir), 4H=1024, K=12
// Inputs: fp32 (+ int32 sentence). Outputs fp32:
//   [0,1024)      path_score [32][32]
//   [1024,17408)  best_path  [32][512] (tags as fp32)
// R14: the LSTM recurrence runs as ONE 1024-thread block PER DIRECTION
// (2 blocks total). 16 waves x 64 gate-rows hold the ENTIRE w_hh of the
// direction in registers (same per-wave footprint as R12). The h exchange
// is now intra-block: the epilogue writes bf16 hi/lo directly into the
// parity-double-buffered LDS hfrag (identical element mapping to R12's
// staging path), and ONE __syncthreads per step replaces the whole
// agent-scope chain (drain + flag RT + poll RT + data RT ~ 4.5us/step).
// No hx, no flags, no atomics, no memset. MFMA chain per accumulator is
// exactly R12's => bit-identical numerics.
// Lessons kept: R9 falsified sc0/local-L2 exchange; R11 falsified 1MB-
// strided mailboxes; R13 falsified intra-step phase splitting (phase
// compute < exchange RT). This removes the exchange instead of hiding it.

typedef __attribute__((ext_vector_type(8))) __bf16 bf16x8;
typedef __attribute__((ext_vector_type(4))) float  f32x4;

#define MFMA16(a, b, c) __builtin_amdgcn_mfma_f32_16x16x32_bf16((a), (b), (c), 0, 0, 0)

__device__ __forceinline__ float sigm(float x) { return 1.0f / (1.0f + __expf(-x)); }
__device__ __forceinline__ float tanh_f(float x) {
  x = fminf(fmaxf(x, -15.0f), 15.0f);
  float e = __expf(2.0f * x);
  return (e - 1.0f) / (e + 1.0f);
}

__device__ __forceinline__ void split8(const float* v, bf16x8& hi, bf16x8& lo) {
#pragma unroll
  for (int j = 0; j < 8; j++) {
    __bf16 h = (__bf16)v[j];
    hi[j] = h;
    lo[j] = (__bf16)(v[j] - (float)h);
  }
}

// ---------------------------------------------------------------------------
// Kernel 1: xg[m=(b,t)][n=(dir,gate,unit)] = embed[sent[m]].w_ih[n] + bias[n]
// M=16384, N=2048, K=512. 128x128 tile/WG, 4 waves 2x2, 3-term hi/lo MFMA.
// ---------------------------------------------------------------------------
__global__ __launch_bounds__(256) void xg_gemm(
    const int* __restrict__ sent, const float* __restrict__ embed,
    const float* __restrict__ wih_f, const float* __restrict__ wih_b,
    const float* __restrict__ bias_f, const float* __restrict__ bias_b,
    float* __restrict__ xg)
{
  __shared__ __bf16 Ah[128][40], Al[128][40];  // 32 k + 8 pad
  __shared__ __bf16 Bh[128][40], Bl[128][40];
  __shared__ int toks[128];
  const int tid = threadIdx.x;
  const int m0 = blockIdx.x * 128, n0 = blockIdx.y * 128;
  if (tid < 128) toks[tid] = sent[m0 + tid];
  const int wave = tid >> 6, lane = tid & 63, q = lane >> 4, c = lane & 15;
  const int wy = wave >> 1, wx = wave & 1;
  f32x4 acc[4][4];
  for (int mt = 0; mt < 4; mt++)
    for (int nt = 0; nt < 4; nt++)
      acc[mt][nt] = f32x4{0.0f, 0.0f, 0.0f, 0.0f};
  __syncthreads();

  for (int k0 = 0; k0 < 512; k0 += 32) {
#pragma unroll
    for (int i = 0; i < 2; i++) {
      int ch = tid + (i << 8);
      int r = ch >> 2, kc = ch & 3;
      float tmp[8];
      const float* asrc = embed + (size_t)toks[r] * 512 + k0 + kc * 8;
#pragma unroll
      for (int j = 0; j < 8; j++) tmp[j] = asrc[j];
      bf16x8 hi, lo;
      split8(tmp, hi, lo);
      *(bf16x8*)&Ah[r][kc * 8] = hi;
      *(bf16x8*)&Al[r][kc * 8] = lo;
      int n = n0 + r;
      const float* wsrc = (n < 1024) ? (wih_f + (size_t)n * 512)
                                     : (wih_b + (size_t)(n - 1024) * 512);
#pragma unroll
      for (int j = 0; j < 8; j++) tmp[j] = wsrc[k0 + kc * 8 + j];
      split8(tmp, hi, lo);
      *(bf16x8*)&Bh[r][kc * 8] = hi;
      *(bf16x8*)&Bl[r][kc * 8] = lo;
    }
    __syncthreads();
    bf16x8 ah[4], al[4], bh[4], bl[4];
#pragma unroll
    for (int t4 = 0; t4 < 4; t4++) {
      int ar = wy * 64 + t4 * 16 + c, br = wx * 64 + t4 * 16 + c;
      ah[t4] = *(const bf16x8*)&Ah[ar][q * 8];
      al[t4] = *(const bf16x8*)&Al[ar][q * 8];
      bh[t4] = *(const bf16x8*)&Bh[br][q * 8];
      bl[t4] = *(const bf16x8*)&Bl[br][q * 8];
    }
#pragma unroll
    for (int mt = 0; mt < 4; mt++)
#pragma unroll
      for (int nt = 0; nt < 4; nt++) {
        acc[mt][nt] = MFMA16(ah[mt], bh[nt], acc[mt][nt]);
        acc[mt][nt] = MFMA16(al[mt], bh[nt], acc[mt][nt]);
        acc[mt][nt] = MFMA16(ah[mt], bl[nt], acc[mt][nt]);
      }
    __syncthreads();
  }

#pragma unroll
  for (int nt = 0; nt < 4; nt++) {
    int n = n0 + wx * 64 + nt * 16 + c;
    float bval = (n < 1024) ? bias_f[n] : bias_b[n - 1024];
#pragma unroll
    for (int mt = 0; mt < 4; mt++) {
      int mbase = m0 + wy * 64 + mt * 16 + q * 4;
#pragma unroll
      for (int reg = 0; reg < 4; reg++)
        xg[(size_t)(mbase + reg) * 2048 + n] = acc[mt][nt][reg] + bval;
    }
  }
}

// ---------------------------------------------------------------------------
// Kernel 2: one LSTM direction per block. 2 blocks x 1024 threads (16 waves).
// Wave w owns gate rows {g*256 + w*16 + c : g=0..3} => the whole w_hh of the
// direction lives in this block's registers. h exchange via LDS hfrag,
// parity double-buffered; ONE __syncthreads per step. Epilogue writes the
// bf16 hi/lo of h directly into hfrag[pn] with the same element mapping
// R12's staging used (verified index-identical).
// ---------------------------------------------------------------------------
__global__ __launch_bounds__(1024, 1) void lstm_rec(
    const float* __restrict__ xg,
    const float* __restrict__ whh_f, const float* __restrict__ whh_b,
    const float* __restrict__ h0, const float* __restrict__ c0,
    float* __restrict__ h_seq)     // [32][512][512]: cols 0-255 fwd, 256-511 bwd
{
  const int d = blockIdx.x;
  const int tid = threadIdx.x;
  const int w = tid >> 6, lane = tid & 63, q = lane >> 4, c = lane & 15;
  const float* __restrict__ whh = d ? whh_b : whh_f;

  __shared__ __bf16 hfrag[2][2][16][512];  // [parity][hi/lo][fid][pos*8+j]

  // weights: wave w, gate g -> rows g*256 + w*16 + c (16 units x 256 k)
  bf16x8 wfh[4][8], wfl[4][8];
#pragma unroll
  for (int g = 0; g < 4; g++) {
    int row = g * 256 + w * 16 + c;
    const float* wr = whh + (size_t)row * 256;
#pragma unroll
    for (int ks = 0; ks < 8; ks++) {
      float tmp[8];
#pragma unroll
      for (int j = 0; j < 8; j++) tmp[j] = wr[ks * 32 + q * 8 + j];
      split8(tmp, wfh[g][ks], wfl[g][ks]);
    }
  }
  const int ug = w * 16 + c;           // unit 0..255
  float cst[2][4];
#pragma unroll
  for (int mt = 0; mt < 2; mt++)
#pragma unroll
    for (int reg = 0; reg < 4; reg++)
      cst[mt][reg] = c0[d * 8192 + (mt * 16 + q * 4 + reg) * 256 + ug];

  // epilogue LDS-write indices (constant per thread except reg/mt)
  const int ekc  = ug >> 3;            // 8-unit chunk 0..31
  const int ej   = ug & 7;             // elem within chunk
  const int efid = ug >> 5;            // k-slice 0..7 (== fid&7 for both mt)
  const int ecidb = ((ekc & 3) << 4);  // cid base (batch part added per reg)

  auto load_xv = [&](float (&xv)[2][4][4], int tt) {
#pragma unroll
    for (int mt = 0; mt < 2; mt++)
#pragma unroll
      for (int reg = 0; reg < 4; reg++) {
        int b = mt * 16 + q * 4 + reg;
        const float* xr = xg + ((size_t)(b * 512 + tt) << 11) + (d << 10) + ug;
#pragma unroll
        for (int g = 0; g < 4; g++)
          xv[mt][g][reg] = xr[g << 8];
      }
  };

  float xv_cur[2][4][4];
  load_xv(xv_cur, d ? 511 : 0);

  // initial stage: h0 -> hfrag[0]  (1024 threads: sb = batch, kc0 = chunk)
  {
    const int sb = tid >> 5;           // 0..31
    const int kc0 = tid & 31;          // 0..31
    float tmp[8];
    const float* src = h0 + d * 8192 + sb * 256 + kc0 * 8;
#pragma unroll
    for (int j = 0; j < 8; j++) tmp[j] = src[j];
    bf16x8 vhi, vlo;
    split8(tmp, vhi, vlo);
    int fid = ((sb >> 4) << 3) + (kc0 >> 2);
    int cid = ((kc0 & 3) << 4) + (sb & 15);
    int pos = cid ^ (fid & 7);
    *(bf16x8*)&hfrag[0][0][fid][pos * 8] = vhi;
    *(bf16x8*)&hfrag[0][1][fid][pos * 8] = vlo;
  }
  __syncthreads();

  for (int s = 0; s < 512; s++) {
    const int t_seq = d ? (511 - s) : s;
    const int p = s & 1, pn = p ^ 1;

    f32x4 acc[2][4];
#pragma unroll
    for (int mt = 0; mt < 2; mt++)
#pragma unroll
      for (int g = 0; g < 4; g++)
#pragma unroll
        for (int reg = 0; reg < 4; reg++)
          acc[mt][g][reg] = xv_cur[mt][g][reg];

    // next step's xg prefetch: issued before MFMA => a full step to land
    float xv_nxt[2][4][4];
    if (s < 511) load_xv(xv_nxt, d ? (511 - (s + 1)) : (s + 1));

#pragma unroll
    for (int ks = 0; ks < 8; ks++) {
      int pos = (lane ^ ks) * 8;
      bf16x8 ahi0 = *(const bf16x8*)&hfrag[p][0][ks][pos];
      bf16x8 ahi1 = *(const bf16x8*)&hfrag[p][0][8 + ks][pos];
      bf16x8 alo0 = *(const bf16x8*)&hfrag[p][1][ks][pos];
      bf16x8 alo1 = *(const bf16x8*)&hfrag[p][1][8 + ks][pos];
#pragma unroll
      for (int g = 0; g < 4; g++) {
        acc[0][g] = MFMA16(ahi0, wfh[g][ks], acc[0][g]);
        acc[1][g] = MFMA16(ahi1, wfh[g][ks], acc[1][g]);
        acc[0][g] = MFMA16(alo0, wfh[g][ks], acc[0][g]);
        acc[1][g] = MFMA16(alo1, wfh[g][ks], acc[1][g]);
        acc[0][g] = MFMA16(ahi0, wfl[g][ks], acc[0][g]);
        acc[1][g] = MFMA16(ahi1, wfl[g][ks], acc[1][g]);
      }
    }

    // epilogue: gates -> h; global h_seq store (fire&forget) + direct LDS
    // publish of bf16 hi/lo into hfrag[pn] (mapping identical to R12 staging)
#pragma unroll
    for (int mt = 0; mt < 2; mt++) {
      const int fid = mt * 8 + efid;
#pragma unroll
      for (int reg = 0; reg < 4; reg++) {
        int b = mt * 16 + q * 4 + reg;
        float iv = sigm(acc[mt][0][reg]);
        float fg = sigm(acc[mt][1][reg]);
        float gv = tanh_f(acc[mt][2][reg]);
        float ov = sigm(acc[mt][3][reg]);
        float cn = fg * cst[mt][reg] + iv * gv;
        cst[mt][reg] = cn;
        float hn = ov * tanh_f(cn);
        h_seq[((size_t)(b * 512 + t_seq) << 9) + (d << 8) + ug] = hn;
        __bf16 hhi = (__bf16)hn;
        __bf16 hlo = (__bf16)(hn - (float)hhi);
        int pos = (ecidb + (q * 4 + reg)) ^ efid;
        hfrag[pn][0][fid][pos * 8 + ej] = hhi;
        hfrag[pn][1][fid][pos * 8 + ej] = hlo;
      }
    }

    if (s < 511) {
#pragma unroll
      for (int mt = 0; mt < 2; mt++)
#pragma unroll
        for (int g = 0; g < 4; g++)
#pragma unroll
          for (int reg = 0; reg < 4; reg++)
            xv_cur[mt][g][reg] = xv_nxt[mt][g][reg];
    }

    __syncthreads();   // hfrag[pn] staged; the ONLY barrier per step
  }
}

// ---------------------------------------------------------------------------
// Kernel 3: feats[m][k] = h_seq[m][:] . W_out[k][:] + b_out[k]   (fp32)
// ---------------------------------------------------------------------------
__global__ __launch_bounds__(256) void feats_k(
    const float* __restrict__ h_seq, const float* __restrict__ W_out,
    const float* __restrict__ b_out, float* __restrict__ feats)
{
  int m = blockIdx.x * 4 + (threadIdx.x >> 6);
  int lane = threadIdx.x & 63;
  const float4* hp = (const float4*)(h_seq + (size_t)m * 512 + lane * 8);
  float4 a = hp[0], b2 = hp[1];
  float h[8] = {a.x, a.y, a.z, a.w, b2.x, b2.y, b2.z, b2.w};
#pragma unroll
  for (int k = 0; k < 12; k++) {
    const float4* wp = (const float4*)(W_out + k * 512 + lane * 8);
    float4 w0 = wp[0], w1 = wp[1];
    float w[8] = {w0.x, w0.y, w0.z, w0.w, w1.x, w1.y, w1.z, w1.w};
    float p = 0.0f;
#pragma unroll
    for (int j = 0; j < 8; j++) p += h[j] * w[j];
#pragma unroll
    for (int off = 32; off > 0; off >>= 1) p += __shfl_xor(p, off);
    if (lane == 0) feats[(size_t)m * 12 + k] = p + b_out[k];
  }
}

// ---------------------------------------------------------------------------
// Kernel 4: Viterbi per batch (one wave). First-max tie-break == jnp.argmax.
// ---------------------------------------------------------------------------
__global__ __launch_bounds__(64) void viterbi_k(
    const float* __restrict__ feats, const float* __restrict__ trans,
    float* __restrict__ terminal, int* __restrict__ best,
    float* __restrict__ out_path)
{
  const int b = blockIdx.x;
  const int lane = threadIdx.x;
  __shared__ unsigned char bp[512][12];
  float trow[12];
#pragma unroll
  for (int pv = 0; pv < 12; pv++)
    trow[pv] = (lane < 12) ? trans[lane * 12 + pv] : -10000.0f;
  float fv = (lane == 10) ? 0.0f : -10000.0f;   // START = 10
  for (int t = 0; t < 512; t++) {
    float bestv = -3.4e38f;
    int arg = 0;
#pragma unroll
    for (int pv = 0; pv < 12; pv++) {
      float sc = __shfl(fv, pv) + trow[pv];
      if (sc > bestv) { bestv = sc; arg = pv; }   // strict > keeps first max
    }
    float ft = (lane < 12) ? feats[(size_t)(b * 512 + t) * 12 + lane] : 0.0f;
    if (lane < 12) {
      bp[t][lane] = (unsigned char)arg;
      fv = bestv + ft;
    }
  }
  float term = fv + ((lane < 12) ? trans[11 * 12 + lane] : 0.0f);  // STOP = 11
  if (lane < 12) terminal[b * 12 + lane] = term;
  float v = (lane < 12) ? term : -3.4e38f;
  int idx = lane;
#pragma unroll
  for (int off = 8; off > 0; off >>= 1) {
    float ov = __shfl_down(v, off);
    int oi = __shfl_down(idx, off);
    if (ov > v || (ov == v && oi < idx)) { v = ov; idx = oi; }
  }
  int bidx = __shfl(idx, 0);
  __syncthreads();
  if (lane == 0) {
    best[b] = bidx;
    int tag = bidx;
    out_path[b * 512 + 511] = (float)bidx;
    for (int t = 511; t >= 1; t--) {
      tag = bp[t][tag];
      out_path[b * 512 + t - 1] = (float)tag;
    }
  }
}

// ---------------------------------------------------------------------------
// Kernel 5: path_score[i][j] = terminal[i][best[j]]
// ---------------------------------------------------------------------------
__global__ __launch_bounds__(256) void pscore_k(
    const float* __restrict__ terminal, const int* __restrict__ best,
    float* __restrict__ out)
{
  int idx = blockIdx.x * 256 + threadIdx.x;
  if (idx < 1024) {
    int i = idx >> 5, j = idx & 31;
    out[idx] = terminal[i * 12 + best[j]];
  }
}

// ---------------------------------------------------------------------------
extern "C" void kernel_launch(void* const* d_in, const int* in_sizes, int n_in,
                              void* d_out, int out_size, void* d_ws, size_t ws_size,
                              hipStream_t stream)
{
  const int*   sent  = (const int*)d_in[0];
  const float* embed = (const float*)d_in[1];
  const float* wih_f = (const float*)d_in[2];
  const float* whh_f = (const float*)d_in[3];
  const float* b_f   = (const float*)d_in[4];
  const float* wih_b = (const float*)d_in[5];
  const float* whh_b = (const float*)d_in[6];
  const float* b_b   = (const float*)d_in[7];
  const float* h0    = (const float*)d_in[8];
  const float* c0    = (const float*)d_in[9];
  const float* W_out = (const float*)d_in[10];
  const float* b_out = (const float*)d_in[11];
  const float* trans = (const float*)d_in[12];

  char* ws = (char*)d_ws;
  float* xg    = (float*)(ws);                    // 134217728 B
  float* h_seq = (float*)(ws + 134217728);        //  33554432 B
  float* feats = (float*)(ws + 167772160);        //    786432 B
  float* term  = (float*)(ws + 168693760);        //      1536 B
  int*   best  = (int*)(ws + 168695296);          //       128 B

  float* outp = (float*)d_out;

  xg_gemm<<<dim3(128, 16), 256, 0, stream>>>(sent, embed, wih_f, wih_b, b_f, b_b, xg);
  lstm_rec<<<2, 1024, 0, stream>>>(xg, whh_f, whh_b, h0, c0, h_seq);
  feats_k<<<4096, 256, 0, stream>>>(h_seq, W_out, b_out, feats);
  viterbi_k<<<32, 64, 0, stream>>>(feats, trans, term, best, outp + 1024);
  pscore_k<<<4, 256, 0, stream>>>(term, best, outp);
}

// Round 8
// 3855.854 us; speedup vs baseline: 5.1783x; 5.1783x over previous
//
#include <hip/hip_runtime.h>
#include <hip/hip_bf16.h>

// BiLSTM-CRF forward: B=32, T=512, E=512, H=256 (per dir), 4H=1024, K=12
// Inputs: fp32 (+ int32 sentence). Outputs fp32:
//   [0,1024)      path_score [32][32]
//   [1024,17408)  best_path  [32][512] (tags as fp32)
// R15 = R12 skeleton (validated 3513us) with latency-exposure fixes only:
//   - 2-step unrolled recurrence loop with NAMED xv double buffers (xvA/xvB,
//     no register copy). R12's xv_cur=xv_nxt copy right after the prefetch
//     issue forced a vmcnt wait that exposed the full xg load RT every step;
//     now the wait lands at next step's acc-init, after poll+staging.
//   - consumer unpack via explicit v_perm_b32 (2 perms/u64) writing u32x4
//     directly to LDS (was ~8 shift/mask/insert ops per u64).
//   - strength-reduced addressing: xg/h_seq element offsets as ints += delta;
//     flag offsets += 16/step. No per-step address recompute.
// Exchange protocol (compact hx u32 pack, agent-scope atomics, per-wave
// store flags, lane-spread __all poll, ONE barrier/step) byte-identical to
// R12. Numerics bit-identical.
// Lessons kept: R9 sc0/L2 falsified; R11 1MB-stride mailbox falsified;
// R13 phase-split falsified; R14 >1 wave/SIMD spills (512-reg/SIMD pool).

typedef __attribute__((ext_vector_type(8))) __bf16 bf16x8;
typedef __attribute__((ext_vector_type(4))) float  f32x4;
typedef __attribute__((ext_vector_type(4))) unsigned int u32x4;

#define MFMA16(a, b, c) __builtin_amdgcn_mfma_f32_16x16x32_bf16((a), (b), (c), 0, 0, 0)

__device__ __forceinline__ float sigm(float x) { return 1.0f / (1.0f + __expf(-x)); }
__device__ __forceinline__ float tanh_f(float x) {
  x = fminf(fmaxf(x, -15.0f), 15.0f);
  float e = __expf(2.0f * x);
  return (e - 1.0f) / (e + 1.0f);
}

__device__ __forceinline__ void split8(const float* v, bf16x8& hi, bf16x8& lo) {
#pragma unroll
  for (int j = 0; j < 8; j++) {
    __bf16 h = (__bf16)v[j];
    hi[j] = h;
    lo[j] = (__bf16)(v[j] - (float)h);
  }
}

// ---------------------------------------------------------------------------
// Kernel 1: xg[m=(b,t)][n=(dir,gate,unit)] = embed[sent[m]].w_ih[n] + bias[n]
// M=16384, N=2048, K=512. 128x128 tile/WG, 4 waves 2x2, 3-term hi/lo MFMA.
// ---------------------------------------------------------------------------
__global__ __launch_bounds__(256) void xg_gemm(
    const int* __restrict__ sent, const float* __restrict__ embed,
    const float* __restrict__ wih_f, const float* __restrict__ wih_b,
    const float* __restrict__ bias_f, const float* __restrict__ bias_b,
    float* __restrict__ xg)
{
  __shared__ __bf16 Ah[128][40], Al[128][40];  // 32 k + 8 pad
  __shared__ __bf16 Bh[128][40], Bl[128][40];
  __shared__ int toks[128];
  const int tid = threadIdx.x;
  const int m0 = blockIdx.x * 128, n0 = blockIdx.y * 128;
  if (tid < 128) toks[tid] = sent[m0 + tid];
  const int wave = tid >> 6, lane = tid & 63, q = lane >> 4, c = lane & 15;
  const int wy = wave >> 1, wx = wave & 1;
  f32x4 acc[4][4];
  for (int mt = 0; mt < 4; mt++)
    for (int nt = 0; nt < 4; nt++)
      acc[mt][nt] = f32x4{0.0f, 0.0f, 0.0f, 0.0f};
  __syncthreads();

  for (int k0 = 0; k0 < 512; k0 += 32) {
#pragma unroll
    for (int i = 0; i < 2; i++) {
      int ch = tid + (i << 8);
      int r = ch >> 2, kc = ch & 3;
      float tmp[8];
      const float* asrc = embed + (size_t)toks[r] * 512 + k0 + kc * 8;
#pragma unroll
      for (int j = 0; j < 8; j++) tmp[j] = asrc[j];
      bf16x8 hi, lo;
      split8(tmp, hi, lo);
      *(bf16x8*)&Ah[r][kc * 8] = hi;
      *(bf16x8*)&Al[r][kc * 8] = lo;
      int n = n0 + r;
      const float* wsrc = (n < 1024) ? (wih_f + (size_t)n * 512)
                                     : (wih_b + (size_t)(n - 1024) * 512);
#pragma unroll
      for (int j = 0; j < 8; j++) tmp[j] = wsrc[k0 + kc * 8 + j];
      split8(tmp, hi, lo);
      *(bf16x8*)&Bh[r][kc * 8] = hi;
      *(bf16x8*)&Bl[r][kc * 8] = lo;
    }
    __syncthreads();
    bf16x8 ah[4], al[4], bh[4], bl[4];
#pragma unroll
    for (int t4 = 0; t4 < 4; t4++) {
      int ar = wy * 64 + t4 * 16 + c, br = wx * 64 + t4 * 16 + c;
      ah[t4] = *(const bf16x8*)&Ah[ar][q * 8];
      al[t4] = *(const bf16x8*)&Al[ar][q * 8];
      bh[t4] = *(const bf16x8*)&Bh[br][q * 8];
      bl[t4] = *(const bf16x8*)&Bl[br][q * 8];
    }
#pragma unroll
    for (int mt = 0; mt < 4; mt++)
#pragma unroll
      for (int nt = 0; nt < 4; nt++) {
        acc[mt][nt] = MFMA16(ah[mt], bh[nt], acc[mt][nt]);
        acc[mt][nt] = MFMA16(al[mt], bh[nt], acc[mt][nt]);
        acc[mt][nt] = MFMA16(ah[mt], bl[nt], acc[mt][nt]);
      }
    __syncthreads();
  }

#pragma unroll
  for (int nt = 0; nt < 4; nt++) {
    int n = n0 + wx * 64 + nt * 16 + c;
    float bval = (n < 1024) ? bias_f[n] : bias_b[n - 1024];
#pragma unroll
    for (int mt = 0; mt < 4; mt++) {
      int mbase = m0 + wy * 64 + mt * 16 + q * 4;
#pragma unroll
      for (int reg = 0; reg < 4; reg++)
        xg[(size_t)(mbase + reg) * 2048 + n] = acc[mt][nt][reg] + bval;
    }
  }
}

// ---------------------------------------------------------------------------
// Kernel 2: both LSTM recurrences. 8 blocks: blk = d*4 + hs. R12 protocol.
// ---------------------------------------------------------------------------
__global__ __launch_bounds__(256, 1) void lstm_rec(
    const float* __restrict__ xg,
    const float* __restrict__ whh_f, const float* __restrict__ whh_b,
    const float* __restrict__ h0, const float* __restrict__ c0,
    float* __restrict__ h_seq,     // [32][512][512]: cols 0-255 fwd, 256-511 bwd
    unsigned int* __restrict__ hx, // [dir][parity][32][256] packed hi/lo bf16
    int* __restrict__ flags)       // [dir][step][16 waves]
{
  const int blk = blockIdx.x;
  const int d = blk >> 2, hs = blk & 3;
  const int tid = threadIdx.x;
  const int wave = tid >> 6, lane = tid & 63, q = lane >> 4, c = lane & 15;
  const float* __restrict__ whh = d ? whh_b : whh_f;

  __shared__ __bf16 hfrag[2][2][16][512];  // [parity][hi/lo][frag][xor-swizzled]

  bf16x8 wfh[4][8], wfl[4][8];
#pragma unroll
  for (int g = 0; g < 4; g++) {
    int row = g * 256 + hs * 64 + wave * 16 + c;   // w_hh row (gate-major)
    const float* wr = whh + (size_t)row * 256;
#pragma unroll
    for (int ks = 0; ks < 8; ks++) {
      float tmp[8];
#pragma unroll
      for (int j = 0; j < 8; j++) tmp[j] = wr[ks * 32 + q * 8 + j];
      split8(tmp, wfh[g][ks], wfl[g][ks]);
    }
  }
  const int ug = hs * 64 + wave * 16 + c;
  float cst[2][4];
#pragma unroll
  for (int mt = 0; mt < 2; mt++)
#pragma unroll
    for (int reg = 0; reg < 4; reg++)
      cst[mt][reg] = c0[d * 8192 + (mt * 16 + q * 4 + reg) * 256 + ug];

  const int sb = tid >> 3;            // staging: batch row
  const int kc4 = (tid & 7) * 4;      // staging: first 8-elem chunk

  // staging LDS indices are per-thread constants
  int fid_c[4], pos_c[4];
#pragma unroll
  for (int i = 0; i < 4; i++) {
    int kc = kc4 + i;
    fid_c[i] = ((sb >> 4) << 3) + (kc >> 2);
    pos_c[i] = ((((kc & 3) << 4) + (sb & 15)) ^ (fid_c[i] & 7));
  }

  // exchange read bases (per parity)
  const unsigned long long* hb64p[2];
  hb64p[0] = (const unsigned long long*)(hx + ((size_t)((d * 2 + 0) * 32 + sb)) * 256 + kc4 * 8);
  hb64p[1] = (const unsigned long long*)(hx + ((size_t)((d * 2 + 1) * 32 + sb)) * 256 + kc4 * 8);
  // exchange write bases (per parity) + per-(mt,reg) batch offsets
  const int hwbase0 = (d * 2 + 0) * 32 * 256 + ug;
  const int hwbase1 = (d * 2 + 1) * 32 * 256 + ug;
  int bof[2][4];
#pragma unroll
  for (int mt = 0; mt < 2; mt++)
#pragma unroll
    for (int reg = 0; reg < 4; reg++)
      bof[mt][reg] = (mt * 16 + q * 4 + reg) * 256;

  int fro = (d * 512) * 16 + (lane & 15);    // flag line polled at step s (holds s-1)
  int fwo = (d * 512) * 16 + hs * 4 + wave;  // flag word written at step s

  const int t0 = d ? 511 : 0;
  const int tdelt = d ? -2048 : 2048;        // xg element-offset delta per step
  const int sdelt = d ? -512 : 512;          // h_seq element-offset delta per step

  int xgo[2][4], hso[2][4];
#pragma unroll
  for (int mt = 0; mt < 2; mt++)
#pragma unroll
    for (int reg = 0; reg < 4; reg++) {
      int b = mt * 16 + q * 4 + reg;
      xgo[mt][reg] = (b * 512 + t0) * 2048 + (d << 10) + ug;
      hso[mt][reg] = (b * 512 + t0) * 512 + (d << 8) + ug;
    }

  float xvA[2][4][4], xvB[2][4][4];
#pragma unroll
  for (int mt = 0; mt < 2; mt++)
#pragma unroll
    for (int reg = 0; reg < 4; reg++)
#pragma unroll
      for (int g = 0; g < 4; g++)
        xvA[mt][g][reg] = xg[xgo[mt][reg] + (g << 8)];

#define LSTM_STEP(S_, P_, XC_, XN_)                                           \
  {                                                                           \
    if ((S_) == 0) {                                                          \
      _Pragma("unroll")                                                       \
      for (int i = 0; i < 4; i++) {                                           \
        int kc = kc4 + i;                                                     \
        float tmp[8];                                                         \
        const float* src = h0 + d * 8192 + sb * 256 + kc * 8;                 \
        _Pragma("unroll")                                                     \
        for (int j = 0; j < 8; j++) tmp[j] = src[j];                          \
        bf16x8 vhi, vlo;                                                      \
        split8(tmp, vhi, vlo);                                                \
        *(bf16x8*)&hfrag[0][0][fid_c[i]][pos_c[i] * 8] = vhi;                 \
        *(bf16x8*)&hfrag[0][1][fid_c[i]][pos_c[i] * 8] = vlo;                 \
      }                                                                       \
    } else {                                                                  \
      int fv = __hip_atomic_load(flags + fro, __ATOMIC_RELAXED,               \
                                 __HIP_MEMORY_SCOPE_AGENT);                   \
      while (!__all(fv == (S_))) {                                            \
        __builtin_amdgcn_s_sleep(1);                                          \
        fv = __hip_atomic_load(flags + fro, __ATOMIC_RELAXED,                 \
                               __HIP_MEMORY_SCOPE_AGENT);                     \
      }                                                                       \
      fro += 16;                                                              \
      unsigned long long v64[16];                                             \
      _Pragma("unroll")                                                       \
      for (int i = 0; i < 16; i++)                                            \
        v64[i] = __hip_atomic_load(hb64p[P_] + i, __ATOMIC_RELAXED,           \
                                   __HIP_MEMORY_SCOPE_AGENT);                 \
      _Pragma("unroll")                                                       \
      for (int i = 0; i < 4; i++) {                                           \
        u32x4 vh, vl;                                                         \
        _Pragma("unroll")                                                     \
        for (int k = 0; k < 4; k++) {                                         \
          unsigned int lo32 = (unsigned int)v64[i * 4 + k];                   \
          unsigned int hi32 = (unsigned int)(v64[i * 4 + k] >> 32);           \
          vh[k] = __builtin_amdgcn_perm(hi32, lo32, 0x07060302u);             \
          vl[k] = __builtin_amdgcn_perm(hi32, lo32, 0x05040100u);             \
        }                                                                     \
        *(u32x4*)&hfrag[P_][0][fid_c[i]][pos_c[i] * 8] = vh;                  \
        *(u32x4*)&hfrag[P_][1][fid_c[i]][pos_c[i] * 8] = vl;                  \
      }                                                                       \
    }                                                                         \
    f32x4 acc[2][4];                                                          \
    _Pragma("unroll")                                                         \
    for (int mt = 0; mt < 2; mt++)                                            \
      _Pragma("unroll")                                                       \
      for (int g = 0; g < 4; g++)                                             \
        _Pragma("unroll")                                                     \
        for (int reg = 0; reg < 4; reg++)                                     \
          acc[mt][g][reg] = XC_[mt][g][reg];                                  \
    __syncthreads();                                                          \
    _Pragma("unroll")                                                         \
    for (int ks = 0; ks < 8; ks++) {                                          \
      int pos = (lane ^ ks) * 8;                                              \
      bf16x8 ahi0 = *(const bf16x8*)&hfrag[P_][0][ks][pos];                   \
      bf16x8 ahi1 = *(const bf16x8*)&hfrag[P_][0][8 + ks][pos];               \
      bf16x8 alo0 = *(const bf16x8*)&hfrag[P_][1][ks][pos];                   \
      bf16x8 alo1 = *(const bf16x8*)&hfrag[P_][1][8 + ks][pos];               \
      _Pragma("unroll")                                                       \
      for (int g = 0; g < 4; g++) {                                           \
        acc[0][g] = MFMA16(ahi0, wfh[g][ks], acc[0][g]);                      \
        acc[1][g] = MFMA16(ahi1, wfh[g][ks], acc[1][g]);                      \
        acc[0][g] = MFMA16(alo0, wfh[g][ks], acc[0][g]);                      \
        acc[1][g] = MFMA16(alo1, wfh[g][ks], acc[1][g]);                      \
        acc[0][g] = MFMA16(ahi0, wfl[g][ks], acc[0][g]);                      \
        acc[1][g] = MFMA16(ahi1, wfl[g][ks], acc[1][g]);                      \
      }                                                                       \
    }                                                                         \
    float hv[2][4];                                                           \
    _Pragma("unroll")                                                         \
    for (int mt = 0; mt < 2; mt++)                                            \
      _Pragma("unroll")                                                       \
      for (int reg = 0; reg < 4; reg++) {                                     \
        float iv = sigm(acc[mt][0][reg]);                                     \
        float fg = sigm(acc[mt][1][reg]);                                     \
        float gv = tanh_f(acc[mt][2][reg]);                                   \
        float ov = sigm(acc[mt][3][reg]);                                     \
        float cn = fg * cst[mt][reg] + iv * gv;                               \
        cst[mt][reg] = cn;                                                    \
        float hn = ov * tanh_f(cn);                                           \
        hv[mt][reg] = hn;                                                     \
        __bf16 hhi = (__bf16)hn;                                              \
        __bf16 hlo = (__bf16)(hn - (float)hhi);                               \
        unsigned int pack =                                                   \
            ((unsigned int)__builtin_bit_cast(unsigned short, hhi) << 16) |   \
            (unsigned int)__builtin_bit_cast(unsigned short, hlo);            \
        __hip_atomic_store(hx + ((P_) ? hwbase0 : hwbase1) + bof[mt][reg],    \
                           pack, __ATOMIC_RELAXED, __HIP_MEMORY_SCOPE_AGENT); \
      }                                                                       \
    asm volatile("s_waitcnt vmcnt(0)" ::: "memory");                          \
    if (lane == 0)                                                            \
      __hip_atomic_store(flags + fwo, (S_) + 1, __ATOMIC_RELAXED,             \
                         __HIP_MEMORY_SCOPE_AGENT);                           \
    fwo += 16;                                                                \
    _Pragma("unroll")                                                         \
    for (int mt = 0; mt < 2; mt++)                                            \
      _Pragma("unroll")                                                       \
      for (int reg = 0; reg < 4; reg++)                                       \
        h_seq[hso[mt][reg]] = hv[mt][reg];                                    \
    if ((S_) < 511) {                                                         \
      _Pragma("unroll")                                                       \
      for (int mt = 0; mt < 2; mt++)                                          \
        _Pragma("unroll")                                                     \
        for (int reg = 0; reg < 4; reg++) {                                   \
          xgo[mt][reg] += tdelt;                                              \
          hso[mt][reg] += sdelt;                                              \
        }                                                                     \
      _Pragma("unroll")                                                       \
      for (int mt = 0; mt < 2; mt++)                                          \
        _Pragma("unroll")                                                     \
        for (int reg = 0; reg < 4; reg++)                                     \
          _Pragma("unroll")                                                   \
          for (int g = 0; g < 4; g++)                                         \
            XN_[mt][g][reg] = xg[xgo[mt][reg] + (g << 8)];                    \
    }                                                                         \
  }

  for (int s = 0; s < 512; s += 2) {
    LSTM_STEP(s,     0, xvA, xvB);
    LSTM_STEP(s + 1, 1, xvB, xvA);
  }
#undef LSTM_STEP
}

// ---------------------------------------------------------------------------
// Kernel 3: feats[m][k] = h_seq[m][:] . W_out[k][:] + b_out[k]   (fp32)
// ---------------------------------------------------------------------------
__global__ __launch_bounds__(256) void feats_k(
    const float* __restrict__ h_seq, const float* __restrict__ W_out,
    const float* __restrict__ b_out, float* __restrict__ feats)
{
  int m = blockIdx.x * 4 + (threadIdx.x >> 6);
  int lane = threadIdx.x & 63;
  const float4* hp = (const float4*)(h_seq + (size_t)m * 512 + lane * 8);
  float4 a = hp[0], b2 = hp[1];
  float h[8] = {a.x, a.y, a.z, a.w, b2.x, b2.y, b2.z, b2.w};
#pragma unroll
  for (int k = 0; k < 12; k++) {
    const float4* wp = (const float4*)(W_out + k * 512 + lane * 8);
    float4 w0 = wp[0], w1 = wp[1];
    float w[8] = {w0.x, w0.y, w0.z, w0.w, w1.x, w1.y, w1.z, w1.w};
    float p = 0.0f;
#pragma unroll
    for (int j = 0; j < 8; j++) p += h[j] * w[j];
#pragma unroll
    for (int off = 32; off > 0; off >>= 1) p += __shfl_xor(p, off);
    if (lane == 0) feats[(size_t)m * 12 + k] = p + b_out[k];
  }
}

// ---------------------------------------------------------------------------
// Kernel 4: Viterbi per batch (one wave). First-max tie-break == jnp.argmax.
// ---------------------------------------------------------------------------
__global__ __launch_bounds__(64) void viterbi_k(
    const float* __restrict__ feats, const float* __restrict__ trans,
    float* __restrict__ terminal, int* __restrict__ best,
    float* __restrict__ out_path)
{
  const int b = blockIdx.x;
  const int lane = threadIdx.x;
  __shared__ unsigned char bp[512][12];
  float trow[12];
#pragma unroll
  for (int pv = 0; pv < 12; pv++)
    trow[pv] = (lane < 12) ? trans[lane * 12 + pv] : -10000.0f;
  float fv = (lane == 10) ? 0.0f : -10000.0f;   // START = 10
  for (int t = 0; t < 512; t++) {
    float bestv = -3.4e38f;
    int arg = 0;
#pragma unroll
    for (int pv = 0; pv < 12; pv++) {
      float sc = __shfl(fv, pv) + trow[pv];
      if (sc > bestv) { bestv = sc; arg = pv; }   // strict > keeps first max
    }
    float ft = (lane < 12) ? feats[(size_t)(b * 512 + t) * 12 + lane] : 0.0f;
    if (lane < 12) {
      bp[t][lane] = (unsigned char)arg;
      fv = bestv + ft;
    }
  }
  float term = fv + ((lane < 12) ? trans[11 * 12 + lane] : 0.0f);  // STOP = 11
  if (lane < 12) terminal[b * 12 + lane] = term;
  float v = (lane < 12) ? term : -3.4e38f;
  int idx = lane;
#pragma unroll
  for (int off = 8; off > 0; off >>= 1) {
    float ov = __shfl_down(v, off);
    int oi = __shfl_down(idx, off);
    if (ov > v || (ov == v && oi < idx)) { v = ov; idx = oi; }
  }
  int bidx = __shfl(idx, 0);
  __syncthreads();
  if (lane == 0) {
    best[b] = bidx;
    int tag = bidx;
    out_path[b * 512 + 511] = (float)bidx;
    for (int t = 511; t >= 1; t--) {
      tag = bp[t][tag];
      out_path[b * 512 + t - 1] = (float)tag;
    }
  }
}

// ---------------------------------------------------------------------------
// Kernel 5: path_score[i][j] = terminal[i][best[j]]
// ---------------------------------------------------------------------------
__global__ __launch_bounds__(256) void pscore_k(
    const float* __restrict__ terminal, const int* __restrict__ best,
    float* __restrict__ out)
{
  int idx = blockIdx.x * 256 + threadIdx.x;
  if (idx < 1024) {
    int i = idx >> 5, j = idx & 31;
    out[idx] = terminal[i * 12 + best[j]];
  }
}

// ---------------------------------------------------------------------------
extern "C" void kernel_launch(void* const* d_in, const int* in_sizes, int n_in,
                              void* d_out, int out_size, void* d_ws, size_t ws_size,
                              hipStream_t stream)
{
  const int*   sent  = (const int*)d_in[0];
  const float* embed = (const float*)d_in[1];
  const float* wih_f = (const float*)d_in[2];
  const float* whh_f = (const float*)d_in[3];
  const float* b_f   = (const float*)d_in[4];
  const float* wih_b = (const float*)d_in[5];
  const float* whh_b = (const float*)d_in[6];
  const float* b_b   = (const float*)d_in[7];
  const float* h0    = (const float*)d_in[8];
  const float* c0    = (const float*)d_in[9];
  const float* W_out = (const float*)d_in[10];
  const float* b_out = (const float*)d_in[11];
  const float* trans = (const float*)d_in[12];

  char* ws = (char*)d_ws;
  float*        xg    = (float*)(ws);                    // 134217728 B
  float*        h_seq = (float*)(ws + 134217728);        //  33554432 B
  float*        feats = (float*)(ws + 167772160);        //    786432 B
  unsigned int* hx    = (unsigned int*)(ws + 168558592); //    131072 B
  int*          flags = (int*)(ws + 168689664);          //     65536 B
  float*        term  = (float*)(ws + 168755200);        //      1536 B
  int*          best  = (int*)(ws + 168756736);          //       128 B

  float* outp = (float*)d_out;

  hipMemsetAsync(flags, 0, 2 * 512 * 16 * sizeof(int), stream);
  xg_gemm<<<dim3(128, 16), 256, 0, stream>>>(sent, embed, wih_f, wih_b, b_f, b_b, xg);
  lstm_rec<<<8, 256, 0, stream>>>(xg, whh_f, whh_b, h0, c0, h_seq, hx, flags);
  feats_k<<<4096, 256, 0, stream>>>(h_seq, W_out, b_out, feats);
  viterbi_k<<<32, 64, 0, stream>>>(feats, trans, term, best, outp + 1024);
  pscore_k<<<4, 256, 0, stream>>>(term, best, outp);
}